// Round 11
// baseline (279.273 us; speedup 1.0000x reference)
//
#include <hip/hip_runtime.h>

// GraphSAGE 3-layer forward: N=50000 nodes, E=800000 edges, F: 96->96->96->48
// out_i = relu( mean_{j in N(i)} h_j @ Wl + h_i @ Wr + b ), x3 layers.
//
// R11: chip-wide plane phasing via kernel boundaries. h stored as 3 bf16
// feature-planes [NPAD][32] (3.2 MB each, fits one 4 MB XCD L2). Per layer:
// 3x gather_plane kernels (each reads ONE plane chip-wide -> L2-resident,
// writes bf16 partial-mean plane), then an LDS-free MFMA kernel reading
// mean/h fragments from global. Adjacency is ushort (node ids < 65536):
// col region 12.8 -> 6.4 MB, 8 ids per 16B load, no LDS staging.

#define NNODES 50000
#define NPAD   50176        // plane row allocation
#define ZROW   50000        // sentinel row (all zeros) in each plane
#define NEDGES 800000
#define CAP    64           // per-node adjacency capacity (max deg ~40 w.h.p.)
#define PL     ((size_t)NPAD * 32)   // shorts per plane
#define EB 3125             // 800000/256 exact
#define CVT_N8 600000       // 50000*96/8
#define CB 2344             // ceil(600000/256)
#define WTN 46080           // 2*96*192 + 48*192
#define WB 180              // ceil(46080/256)
#define GB 782              // ceil(50000*4/256) gather blocks

typedef __attribute__((ext_vector_type(8))) short bf16x8;
typedef __attribute__((ext_vector_type(4))) float f32x4;

__device__ inline unsigned short f2bf(float f) {
    unsigned int u = __float_as_uint(f);
    unsigned int r = (u + 0x7fffu + ((u >> 16) & 1u)) >> 16;   // RNE
    return (unsigned short)r;
}
__device__ inline float bf2f_lo(unsigned int u) { return __uint_as_float(u << 16); }
__device__ inline float bf2f_hi(unsigned int u) { return __uint_as_float(u & 0xffff0000u); }

// ---------------- pass 1: slotted ushort adjacency + converts + zero-rows ----------------
// blocks [0,EB): edges; [EB,EB+CB): x->bf16 planes; next WB: WT prep; last 1: zero rows.
__global__ void build_cvt(const int* __restrict__ src, const int* __restrict__ dst,
                          int* __restrict__ deg, unsigned short* __restrict__ colu,
                          const float* __restrict__ x, unsigned short* __restrict__ h0b,
                          unsigned short* __restrict__ h1b, unsigned short* __restrict__ h2b,
                          const float* __restrict__ Wl0, const float* __restrict__ Wr0,
                          const float* __restrict__ Wl1, const float* __restrict__ Wr1,
                          const float* __restrict__ Wl2, const float* __restrict__ Wr2,
                          unsigned short* __restrict__ WT0, unsigned short* __restrict__ WT1,
                          unsigned short* __restrict__ WT2) {
    int b = blockIdx.x;
    if (b < EB) {
        int e = b * 256 + threadIdx.x;                 // exact: EB*256 == NEDGES
        int d = dst[e];
        int r = atomicAdd(&deg[d], 1);
        if (r < CAP) colu[(size_t)d * CAP + r] = (unsigned short)src[e];
    } else if (b < EB + CB) {
        long long t = (long long)(b - EB) * 256 + threadIdx.x;
        if (t < CVT_N8) {
            int n = (int)(t / 12);
            int c = (int)(t - (long long)n * 12);      // 8-feat chunk 0..11
            int pp = c >> 2;                           // plane
            int c4 = c & 3;
            const float4* p4 = reinterpret_cast<const float4*>(x + (size_t)n * 96 + c * 8);
            float4 a = p4[0], cc = p4[1];
            uint4 o;
            o.x = (unsigned)f2bf(a.x) | ((unsigned)f2bf(a.y) << 16);
            o.y = (unsigned)f2bf(a.z) | ((unsigned)f2bf(a.w) << 16);
            o.z = (unsigned)f2bf(cc.x) | ((unsigned)f2bf(cc.y) << 16);
            o.w = (unsigned)f2bf(cc.z) | ((unsigned)f2bf(cc.w) << 16);
            *reinterpret_cast<uint4*>(h0b + (size_t)pp * PL + (size_t)n * 32 + c4 * 8) = o;
        }
    } else if (b < EB + CB + WB) {
        int t = (b - EB - CB) * 256 + threadIdx.x;
        if (t >= WTN) return;
        const float* Wl; const float* Wr; unsigned short* WT; int fout; int u;
        if (t < 18432)      { Wl = Wl0; Wr = Wr0; WT = WT0; fout = 96; u = t; }
        else if (t < 36864) { Wl = Wl1; Wr = Wr1; WT = WT1; fout = 96; u = t - 18432; }
        else                { Wl = Wl2; Wr = Wr2; WT = WT2; fout = 48; u = t - 36864; }
        int j = u / 192;
        int k = u - j * 192;
        float v = (k < 96) ? Wl[k * fout + j] : Wr[(k - 96) * fout + j];
        WT[u] = f2bf(v);
    } else {
        // zero the sentinel rows: 3 buffers x 3 planes x 64B = 36 uint4 stores
        int t = threadIdx.x;
        if (t < 36) {
            uint4 z = make_uint4(0, 0, 0, 0);
            unsigned short* base = (t < 12) ? h0b : (t < 24) ? h1b : h2b;
            int u = t % 12;
            int pp = u >> 2;            // plane
            int s = u & 3;              // 16B chunk within 64B row
            *reinterpret_cast<uint4*>(base + (size_t)pp * PL + (size_t)ZROW * 32 + s * 8) = z;
        }
    }
}

// ---------------- per-plane gather-mean (one 3.2 MB plane chip-wide) ----------------
// Thread = (node, 16B chunk-of-4): 4 threads cover a node's 64B plane row.
// Loop: one 16B colu load gives 8 neighbor ids (sanitized vs deg); 8
// outstanding 16B gathers from the single plane; fp32 accumulate; bf16 mean.
__global__ __launch_bounds__(256) void gather_plane(
    const unsigned short* __restrict__ plane,    // [NPAD][32] bf16
    const int* __restrict__ deg,
    const unsigned short* __restrict__ colu,     // [NPAD][CAP]
    unsigned short* __restrict__ meanp) {        // [NPAD][32] bf16 out
    int t = blockIdx.x * 256 + threadIdx.x;
    int node = t >> 2;
    if (node >= NNODES) return;
    const int coff = (t & 3) * 8;
    const int d = deg[node];
    const int pd = (d + 7) & ~7;
    const unsigned short* __restrict__ cl = colu + (size_t)node * CAP;
    float a0 = 0.f, a1 = 0.f, a2 = 0.f, a3 = 0.f, a4 = 0.f, a5 = 0.f, a6 = 0.f, a7 = 0.f;
    for (int j = 0; j < pd; j += 8) {
        uint4 cu = *reinterpret_cast<const uint4*>(cl + j);
        int s0 = (j + 0 < d) ? (int)(cu.x & 0xffffu) : ZROW;
        int s1 = (j + 1 < d) ? (int)(cu.x >> 16)     : ZROW;
        int s2 = (j + 2 < d) ? (int)(cu.y & 0xffffu) : ZROW;
        int s3 = (j + 3 < d) ? (int)(cu.y >> 16)     : ZROW;
        int s4 = (j + 4 < d) ? (int)(cu.z & 0xffffu) : ZROW;
        int s5 = (j + 5 < d) ? (int)(cu.z >> 16)     : ZROW;
        int s6 = (j + 6 < d) ? (int)(cu.w & 0xffffu) : ZROW;
        int s7 = (j + 7 < d) ? (int)(cu.w >> 16)     : ZROW;
        uint4 u0 = *reinterpret_cast<const uint4*>(plane + (size_t)s0 * 32 + coff);
        uint4 u1 = *reinterpret_cast<const uint4*>(plane + (size_t)s1 * 32 + coff);
        uint4 u2 = *reinterpret_cast<const uint4*>(plane + (size_t)s2 * 32 + coff);
        uint4 u3 = *reinterpret_cast<const uint4*>(plane + (size_t)s3 * 32 + coff);
        uint4 u4 = *reinterpret_cast<const uint4*>(plane + (size_t)s4 * 32 + coff);
        uint4 u5 = *reinterpret_cast<const uint4*>(plane + (size_t)s5 * 32 + coff);
        uint4 u6 = *reinterpret_cast<const uint4*>(plane + (size_t)s6 * 32 + coff);
        uint4 u7 = *reinterpret_cast<const uint4*>(plane + (size_t)s7 * 32 + coff);
        a0 += bf2f_lo(u0.x) + bf2f_lo(u1.x) + bf2f_lo(u2.x) + bf2f_lo(u3.x)
            + bf2f_lo(u4.x) + bf2f_lo(u5.x) + bf2f_lo(u6.x) + bf2f_lo(u7.x);
        a1 += bf2f_hi(u0.x) + bf2f_hi(u1.x) + bf2f_hi(u2.x) + bf2f_hi(u3.x)
            + bf2f_hi(u4.x) + bf2f_hi(u5.x) + bf2f_hi(u6.x) + bf2f_hi(u7.x);
        a2 += bf2f_lo(u0.y) + bf2f_lo(u1.y) + bf2f_lo(u2.y) + bf2f_lo(u3.y)
            + bf2f_lo(u4.y) + bf2f_lo(u5.y) + bf2f_lo(u6.y) + bf2f_lo(u7.y);
        a3 += bf2f_hi(u0.y) + bf2f_hi(u1.y) + bf2f_hi(u2.y) + bf2f_hi(u3.y)
            + bf2f_hi(u4.y) + bf2f_hi(u5.y) + bf2f_hi(u6.y) + bf2f_hi(u7.y);
        a4 += bf2f_lo(u0.z) + bf2f_lo(u1.z) + bf2f_lo(u2.z) + bf2f_lo(u3.z)
            + bf2f_lo(u4.z) + bf2f_lo(u5.z) + bf2f_lo(u6.z) + bf2f_lo(u7.z);
        a5 += bf2f_hi(u0.z) + bf2f_hi(u1.z) + bf2f_hi(u2.z) + bf2f_hi(u3.z)
            + bf2f_hi(u4.z) + bf2f_hi(u5.z) + bf2f_hi(u6.z) + bf2f_hi(u7.z);
        a6 += bf2f_lo(u0.w) + bf2f_lo(u1.w) + bf2f_lo(u2.w) + bf2f_lo(u3.w)
            + bf2f_lo(u4.w) + bf2f_lo(u5.w) + bf2f_lo(u6.w) + bf2f_lo(u7.w);
        a7 += bf2f_hi(u0.w) + bf2f_hi(u1.w) + bf2f_hi(u2.w) + bf2f_hi(u3.w)
            + bf2f_hi(u4.w) + bf2f_hi(u5.w) + bf2f_hi(u6.w) + bf2f_hi(u7.w);
    }
    float inv = (d > 0) ? 1.0f / (float)d : 0.0f;
    uint4 o;
    o.x = (unsigned)f2bf(a0 * inv) | ((unsigned)f2bf(a1 * inv) << 16);
    o.y = (unsigned)f2bf(a2 * inv) | ((unsigned)f2bf(a3 * inv) << 16);
    o.z = (unsigned)f2bf(a4 * inv) | ((unsigned)f2bf(a5 * inv) << 16);
    o.w = (unsigned)f2bf(a6 * inv) | ((unsigned)f2bf(a7 * inv) << 16);
    *reinterpret_cast<uint4*>(meanp + (size_t)node * 32 + coff) = o;
}

// ---------------- LDS-free MFMA GEMM: out = relu([mean|h] @ [Wl;Wr] + b) ----------------
// Block = 16 nodes, 256 threads, 4 waves; wave w does N-tiles w, w+4, ...
// A-frags read directly from mean/h planes (16B global loads).
// A-frag (16x16x32 bf16): lane holds A[m=lane&15][k=(lane>>4)*8+0..7]
// B-frag: lane holds B[k=(lane>>4)*8+0..7][n=lane&15] -> WT[n][k] rows
// C/D: col=lane&15, row=(lane>>4)*4+reg  (verified layout, m89)
template <int NT, bool WRITE_BF16>
__global__ __launch_bounds__(256) void sage_mfma(
    const unsigned short* __restrict__ meanP,    // 3 planes [NPAD][32]
    const unsigned short* __restrict__ hb,       // 3 planes [NPAD][32]
    const unsigned short* __restrict__ WT,       // [16*NT][192]
    const float* __restrict__ bias,              // [16*NT]
    unsigned short* __restrict__ out_bf,         // next h planes
    float* __restrict__ out_f) {
    const int i0 = blockIdx.x * 16;
    const int t = threadIdx.x;
    const int wave = t >> 6;
    const int lane = t & 63;
    const int m = lane & 15;
    const int kq = (lane >> 4) * 8;

    bf16x8 afr[6];
#pragma unroll
    for (int kk = 0; kk < 3; ++kk)
        afr[kk] = *reinterpret_cast<const bf16x8*>(
            meanP + (size_t)kk * PL + (size_t)(i0 + m) * 32 + kq);
#pragma unroll
    for (int kk = 0; kk < 3; ++kk)
        afr[3 + kk] = *reinterpret_cast<const bf16x8*>(
            hb + (size_t)kk * PL + (size_t)(i0 + m) * 32 + kq);

    const int r0 = (lane >> 4) * 4;
    for (int nt = wave; nt < NT; nt += 4) {
        f32x4 acc = {0.f, 0.f, 0.f, 0.f};
        const unsigned short* wrow = WT + (size_t)(nt * 16 + m) * 192 + kq;
#pragma unroll
        for (int kk = 0; kk < 6; ++kk) {
            bf16x8 bfr = *reinterpret_cast<const bf16x8*>(wrow + kk * 32);
            acc = __builtin_amdgcn_mfma_f32_16x16x32_bf16(afr[kk], bfr, acc, 0, 0, 0);
        }
        int colj = nt * 16 + m;
        float bv = bias[colj];
#pragma unroll
        for (int r = 0; r < 4; ++r) {
            float v = fmaxf(acc[r] + bv, 0.0f);
            int row = i0 + r0 + r;
            if (WRITE_BF16) {
                out_bf[(size_t)(colj >> 5) * PL + (size_t)row * 32 + (colj & 31)] = f2bf(v);
            } else {
                out_f[(size_t)row * (16 * NT) + colj] = v;
            }
        }
    }
}

extern "C" void kernel_launch(void* const* d_in, const int* in_sizes, int n_in,
                              void* d_out, int out_size, void* d_ws, size_t ws_size,
                              hipStream_t stream) {
    const float* x   = (const float*)d_in[0];
    const int*   ei  = (const int*)d_in[1];   // [2, E]: row0 = src, row1 = dst
    const float* Wl0 = (const float*)d_in[2];
    const float* Wr0 = (const float*)d_in[3];
    const float* b0  = (const float*)d_in[4];
    const float* Wl1 = (const float*)d_in[5];
    const float* Wr1 = (const float*)d_in[6];
    const float* b1  = (const float*)d_in[7];
    const float* Wl2 = (const float*)d_in[8];
    const float* Wr2 = (const float*)d_in[9];
    const float* b2  = (const float*)d_in[10];
    float* out = (float*)d_out;

    const int* src = ei;
    const int* dst = ei + NEDGES;

    // workspace layout (h buffers = 3 planes of [NPAD][32] bf16 each)
    char* p = (char*)d_ws;
    int* deg = (int*)p;                        p += (size_t)NPAD * 4;
    unsigned short* colu = (unsigned short*)p; p += (size_t)NPAD * CAP * 2;   // 6.4 MB
    unsigned short* WT0 = (unsigned short*)p;  p += 96 * 192 * 2;
    unsigned short* WT1 = (unsigned short*)p;  p += 96 * 192 * 2;
    unsigned short* WT2 = (unsigned short*)p;  p += 48 * 192 * 2;
    unsigned short* h0b = (unsigned short*)p;  p += 3 * PL * 2;
    unsigned short* h1b = (unsigned short*)p;  p += 3 * PL * 2;
    unsigned short* h2b = (unsigned short*)p;  p += 3 * PL * 2;
    unsigned short* mP  = (unsigned short*)p;  p += 3 * PL * 2;

    // ---- adjacency build + converts (one grid) ----
    hipMemsetAsync(deg, 0, (size_t)NPAD * sizeof(int), stream);
    build_cvt<<<EB + CB + WB + 1, 256, 0, stream>>>(
        src, dst, deg, colu, x, h0b, h1b, h2b,
        Wl0, Wr0, Wl1, Wr1, Wl2, Wr2, WT0, WT1, WT2);

    const int LB = NNODES / 16;   // 3125 exact

    // ---- layer 0 ----
    gather_plane<<<GB, 256, 0, stream>>>(h0b + 0 * PL, deg, colu, mP + 0 * PL);
    gather_plane<<<GB, 256, 0, stream>>>(h0b + 1 * PL, deg, colu, mP + 1 * PL);
    gather_plane<<<GB, 256, 0, stream>>>(h0b + 2 * PL, deg, colu, mP + 2 * PL);
    sage_mfma<6, true><<<LB, 256, 0, stream>>>(mP, h0b, WT0, b0, h1b, nullptr);
    // ---- layer 1 ----
    gather_plane<<<GB, 256, 0, stream>>>(h1b + 0 * PL, deg, colu, mP + 0 * PL);
    gather_plane<<<GB, 256, 0, stream>>>(h1b + 1 * PL, deg, colu, mP + 1 * PL);
    gather_plane<<<GB, 256, 0, stream>>>(h1b + 2 * PL, deg, colu, mP + 2 * PL);
    sage_mfma<6, true><<<LB, 256, 0, stream>>>(mP, h1b, WT1, b1, h2b, nullptr);
    // ---- layer 2 ----
    gather_plane<<<GB, 256, 0, stream>>>(h2b + 0 * PL, deg, colu, mP + 0 * PL);
    gather_plane<<<GB, 256, 0, stream>>>(h2b + 1 * PL, deg, colu, mP + 1 * PL);
    gather_plane<<<GB, 256, 0, stream>>>(h2b + 2 * PL, deg, colu, mP + 2 * PL);
    sage_mfma<3, false><<<LB, 256, 0, stream>>>(mP, h2b, WT2, b2, nullptr, out);
}

// Round 12
// 223.347 us; speedup vs baseline: 1.2504x; 1.2504x over previous
//
#include <hip/hip_runtime.h>

// GraphSAGE 3-layer forward: N=50000 nodes, E=800000 edges, F: 96->96->96->48
// out_i = relu( mean_{j in N(i)} h_j @ Wl + h_i @ Wr + b ), x3 layers.
//
// R12: revert to R7 structure (best: 225.7us, 5 dispatches) + ushort
// adjacency (ids < 65536): col footprint 12.8 -> 6.4 MB; per-XCD write
// working set 3.2 MB < 4 MB L2 -> build write-amp drops. Layer kernel
// stages 2 KB of ushort ids per block. Gather/MFMA unchanged from R7.

#define NNODES 50000
#define NROWS  50001        // h rows incl. sentinel
#define ZROW   50000        // sentinel row (all zeros) in each h buffer
#define NEDGES 800000
#define CAP    64           // per-node adjacency capacity (max deg ~40 w.h.p.)
#define LSTR   72           // LDS cols stride in ushorts (144B -> bank-spread)
#define EB 3125             // 800000/256 exact
#define CVT_N8 600000       // 50000*96/8
#define CB 2344             // ceil(600000/256)
#define WTN 46080           // 2*96*192 + 48*192
#define WB 180              // ceil(46080/256)

typedef __attribute__((ext_vector_type(8))) short bf16x8;
typedef __attribute__((ext_vector_type(4))) float f32x4;

__device__ inline unsigned short f2bf(float f) {
    unsigned int u = __float_as_uint(f);
    unsigned int r = (u + 0x7fffu + ((u >> 16) & 1u)) >> 16;   // RNE
    return (unsigned short)r;
}
__device__ inline float bf2f_lo(unsigned int u) { return __uint_as_float(u << 16); }
__device__ inline float bf2f_hi(unsigned int u) { return __uint_as_float(u & 0xffff0000u); }

// ---------------- pass 1: slotted ushort adjacency + converts + zero-rows ----------------
// blocks [0,EB): edges; [EB,EB+CB): x->bf16; next WB: WT prep; last 1: zero rows.
__global__ void build_cvt(const int* __restrict__ src, const int* __restrict__ dst,
                          int* __restrict__ deg, unsigned short* __restrict__ colu,
                          const float* __restrict__ x, unsigned short* __restrict__ h0b,
                          unsigned short* __restrict__ h1b, unsigned short* __restrict__ h2b,
                          const float* __restrict__ Wl0, const float* __restrict__ Wr0,
                          const float* __restrict__ Wl1, const float* __restrict__ Wr1,
                          const float* __restrict__ Wl2, const float* __restrict__ Wr2,
                          unsigned short* __restrict__ WT0, unsigned short* __restrict__ WT1,
                          unsigned short* __restrict__ WT2) {
    int b = blockIdx.x;
    if (b < EB) {
        int e = b * 256 + threadIdx.x;                 // exact: EB*256 == NEDGES
        int d = dst[e];
        int r = atomicAdd(&deg[d], 1);
        if (r < CAP) colu[(size_t)d * CAP + r] = (unsigned short)src[e];
    } else if (b < EB + CB) {
        long long t = (long long)(b - EB) * 256 + threadIdx.x;
        if (t < CVT_N8) {
            const float4* p = reinterpret_cast<const float4*>(x + t * 8);
            float4 a = p[0], c = p[1];
            uint4 o;
            o.x = (unsigned)f2bf(a.x) | ((unsigned)f2bf(a.y) << 16);
            o.y = (unsigned)f2bf(a.z) | ((unsigned)f2bf(a.w) << 16);
            o.z = (unsigned)f2bf(c.x) | ((unsigned)f2bf(c.y) << 16);
            o.w = (unsigned)f2bf(c.z) | ((unsigned)f2bf(c.w) << 16);
            *reinterpret_cast<uint4*>(h0b + t * 8) = o;
        }
    } else if (b < EB + CB + WB) {
        int t = (b - EB - CB) * 256 + threadIdx.x;
        if (t >= WTN) return;
        const float* Wl; const float* Wr; unsigned short* WT; int fout; int u;
        if (t < 18432)      { Wl = Wl0; Wr = Wr0; WT = WT0; fout = 96; u = t; }
        else if (t < 36864) { Wl = Wl1; Wr = Wr1; WT = WT1; fout = 96; u = t - 18432; }
        else                { Wl = Wl2; Wr = Wr2; WT = WT2; fout = 48; u = t - 36864; }
        int j = u / 192;
        int k = u - j * 192;
        float v = (k < 96) ? Wl[k * fout + j] : Wr[(k - 96) * fout + j];
        WT[u] = f2bf(v);
    } else {
        // zero the sentinel rows: 3 buffers x 96 shorts = 36 uint4 stores
        int t = threadIdx.x;
        if (t < 36) {
            uint4 z = make_uint4(0, 0, 0, 0);
            unsigned short* base = (t < 12) ? h0b : (t < 24) ? h1b : h2b;
            int c = (t % 12) * 8;
            *reinterpret_cast<uint4*>(base + (size_t)ZROW * 96 + c) = z;
        }
    }
}

// ---------------- fused gather-mean + dual MFMA GEMM + bias + relu ----------------
// Block = 16 nodes, 256 threads. Stage 16*CAP ushort slots (2 KB) into LDS
// (stride LSTR, sanitized: slot>=deg -> ZROW). Threads 0..191 gather-mean
// (8-wide, 8 outstanding 16B loads) into Asm; 4 waves run the K=192
// [mean|h] @ [Wl;Wr] MFMA, N-tiles strided across waves.
// A-frag (16x16x32 bf16): lane holds A[m=lane&15][k=(lane>>4)*8+0..7]
// B-frag: lane holds B[k=(lane>>4)*8+0..7][n=lane&15] -> WT[n][k] rows
// C/D: col=lane&15, row=(lane>>4)*4+reg  (verified layout, m89)
template <int NT, bool WRITE_BF16>
__global__ __launch_bounds__(256) void fused_layer(
    const unsigned short* __restrict__ hb,
    const int* __restrict__ deg, const unsigned short* __restrict__ colu,
    const unsigned short* __restrict__ WT,   // [16*NT][192]
    const float* __restrict__ bias,          // [16*NT]
    unsigned short* __restrict__ out_bf, float* __restrict__ out_f) {
    __shared__ unsigned short Asm[16][200];
    __shared__ unsigned short cols[16 * LSTR];
    const int i0 = blockIdx.x * 16;
    const int t = threadIdx.x;

    // ---- stage + sanitize adjacency: 1024 ushorts, 4 per thread ----
    {
        int u4 = t * 4;                      // ushort index 0..1020
        int node = u4 >> 6;                  // CAP=64
        int slot = u4 & 63;
        uint2 v = *reinterpret_cast<const uint2*>(colu + (size_t)(i0 + node) * CAP + slot);
        int d = deg[i0 + node];
        unsigned int s0 = (slot + 0 < d) ? (v.x & 0xffffu) : ZROW;
        unsigned int s1 = (slot + 1 < d) ? (v.x >> 16)     : ZROW;
        unsigned int s2 = (slot + 2 < d) ? (v.y & 0xffffu) : ZROW;
        unsigned int s3 = (slot + 3 < d) ? (v.y >> 16)     : ZROW;
        uint2 o;
        o.x = s0 | (s1 << 16);
        o.y = s2 | (s3 << 16);
        *reinterpret_cast<uint2*>(&cols[node * LSTR + slot]) = o;
    }
    __syncthreads();

    if (t < 192) {
        const int nl = t / 12;
        const int c = (t - nl * 12) * 8;
        const int d = deg[i0 + nl];
        const int pd = (d + 7) & ~7;
        float a0 = 0.f, a1 = 0.f, a2 = 0.f, a3 = 0.f, a4 = 0.f, a5 = 0.f, a6 = 0.f, a7 = 0.f;
        for (int j = 0; j < pd; j += 8) {
            uint4 cu = *reinterpret_cast<const uint4*>(&cols[nl * LSTR + j]);
            int s0 = (int)(cu.x & 0xffffu), s1 = (int)(cu.x >> 16);
            int s2 = (int)(cu.y & 0xffffu), s3 = (int)(cu.y >> 16);
            int s4 = (int)(cu.z & 0xffffu), s5 = (int)(cu.z >> 16);
            int s6 = (int)(cu.w & 0xffffu), s7 = (int)(cu.w >> 16);
            uint4 u0 = *reinterpret_cast<const uint4*>(hb + (size_t)s0 * 96 + c);
            uint4 u1 = *reinterpret_cast<const uint4*>(hb + (size_t)s1 * 96 + c);
            uint4 u2 = *reinterpret_cast<const uint4*>(hb + (size_t)s2 * 96 + c);
            uint4 u3 = *reinterpret_cast<const uint4*>(hb + (size_t)s3 * 96 + c);
            uint4 u4 = *reinterpret_cast<const uint4*>(hb + (size_t)s4 * 96 + c);
            uint4 u5 = *reinterpret_cast<const uint4*>(hb + (size_t)s5 * 96 + c);
            uint4 u6 = *reinterpret_cast<const uint4*>(hb + (size_t)s6 * 96 + c);
            uint4 u7 = *reinterpret_cast<const uint4*>(hb + (size_t)s7 * 96 + c);
            a0 += bf2f_lo(u0.x) + bf2f_lo(u1.x) + bf2f_lo(u2.x) + bf2f_lo(u3.x)
                + bf2f_lo(u4.x) + bf2f_lo(u5.x) + bf2f_lo(u6.x) + bf2f_lo(u7.x);
            a1 += bf2f_hi(u0.x) + bf2f_hi(u1.x) + bf2f_hi(u2.x) + bf2f_hi(u3.x)
                + bf2f_hi(u4.x) + bf2f_hi(u5.x) + bf2f_hi(u6.x) + bf2f_hi(u7.x);
            a2 += bf2f_lo(u0.y) + bf2f_lo(u1.y) + bf2f_lo(u2.y) + bf2f_lo(u3.y)
                + bf2f_lo(u4.y) + bf2f_lo(u5.y) + bf2f_lo(u6.y) + bf2f_lo(u7.y);
            a3 += bf2f_hi(u0.y) + bf2f_hi(u1.y) + bf2f_hi(u2.y) + bf2f_hi(u3.y)
                + bf2f_hi(u4.y) + bf2f_hi(u5.y) + bf2f_hi(u6.y) + bf2f_hi(u7.y);
            a4 += bf2f_lo(u0.z) + bf2f_lo(u1.z) + bf2f_lo(u2.z) + bf2f_lo(u3.z)
                + bf2f_lo(u4.z) + bf2f_lo(u5.z) + bf2f_lo(u6.z) + bf2f_lo(u7.z);
            a5 += bf2f_hi(u0.z) + bf2f_hi(u1.z) + bf2f_hi(u2.z) + bf2f_hi(u3.z)
                + bf2f_hi(u4.z) + bf2f_hi(u5.z) + bf2f_hi(u6.z) + bf2f_hi(u7.z);
            a6 += bf2f_lo(u0.w) + bf2f_lo(u1.w) + bf2f_lo(u2.w) + bf2f_lo(u3.w)
                + bf2f_lo(u4.w) + bf2f_lo(u5.w) + bf2f_lo(u6.w) + bf2f_lo(u7.w);
            a7 += bf2f_hi(u0.w) + bf2f_hi(u1.w) + bf2f_hi(u2.w) + bf2f_hi(u3.w)
                + bf2f_hi(u4.w) + bf2f_hi(u5.w) + bf2f_hi(u6.w) + bf2f_hi(u7.w);
        }
        float inv = (d > 0) ? 1.0f / (float)d : 0.0f;
        uint4 o;
        o.x = (unsigned)f2bf(a0 * inv) | ((unsigned)f2bf(a1 * inv) << 16);
        o.y = (unsigned)f2bf(a2 * inv) | ((unsigned)f2bf(a3 * inv) << 16);
        o.z = (unsigned)f2bf(a4 * inv) | ((unsigned)f2bf(a5 * inv) << 16);
        o.w = (unsigned)f2bf(a6 * inv) | ((unsigned)f2bf(a7 * inv) << 16);
        *reinterpret_cast<uint4*>(&Asm[nl][c]) = o;
    }
    __syncthreads();

    const int wave = t >> 6;
    const int lane = t & 63;
    const int m = lane & 15;
    const int kq = (lane >> 4) * 8;

    bf16x8 afr[6];
#pragma unroll
    for (int kk = 0; kk < 3; ++kk)
        afr[kk] = *reinterpret_cast<const bf16x8*>(&Asm[m][kq + kk * 32]);
    const unsigned short* hrow = hb + (size_t)(i0 + m) * 96 + kq;
#pragma unroll
    for (int kk = 0; kk < 3; ++kk)
        afr[3 + kk] = *reinterpret_cast<const bf16x8*>(hrow + kk * 32);

    const int r0 = (lane >> 4) * 4;
    for (int nt = wave; nt < NT; nt += 4) {
        f32x4 acc = {0.f, 0.f, 0.f, 0.f};
        const unsigned short* wrow = WT + (size_t)(nt * 16 + m) * 192 + kq;
#pragma unroll
        for (int kk = 0; kk < 6; ++kk) {
            bf16x8 bfr = *reinterpret_cast<const bf16x8*>(wrow + kk * 32);
            acc = __builtin_amdgcn_mfma_f32_16x16x32_bf16(afr[kk], bfr, acc, 0, 0, 0);
        }
        int colj = nt * 16 + m;
        float bv = bias[colj];
#pragma unroll
        for (int r = 0; r < 4; ++r) {
            float v = fmaxf(acc[r] + bv, 0.0f);
            size_t oi = (size_t)(i0 + r0 + r) * (16 * NT) + colj;
            if (WRITE_BF16) out_bf[oi] = f2bf(v);
            else            out_f[oi] = v;
        }
    }
}

extern "C" void kernel_launch(void* const* d_in, const int* in_sizes, int n_in,
                              void* d_out, int out_size, void* d_ws, size_t ws_size,
                              hipStream_t stream) {
    const float* x   = (const float*)d_in[0];
    const int*   ei  = (const int*)d_in[1];   // [2, E]: row0 = src, row1 = dst
    const float* Wl0 = (const float*)d_in[2];
    const float* Wr0 = (const float*)d_in[3];
    const float* b0  = (const float*)d_in[4];
    const float* Wl1 = (const float*)d_in[5];
    const float* Wr1 = (const float*)d_in[6];
    const float* b1  = (const float*)d_in[7];
    const float* Wl2 = (const float*)d_in[8];
    const float* Wr2 = (const float*)d_in[9];
    const float* b2  = (const float*)d_in[10];
    float* out = (float*)d_out;

    const int* src = ei;
    const int* dst = ei + NEDGES;

    // workspace layout
    char* p = (char*)d_ws;
    int* deg = (int*)p;                        p += (size_t)50176 * 4;
    unsigned short* colu = (unsigned short*)p; p += (size_t)50176 * CAP * 2;  // 6.4 MB
    unsigned short* WT0 = (unsigned short*)p;  p += 96 * 192 * 2;
    unsigned short* WT1 = (unsigned short*)p;  p += 96 * 192 * 2;
    unsigned short* WT2 = (unsigned short*)p;  p += 48 * 192 * 2;
    unsigned short* h0b = (unsigned short*)p;  p += (size_t)NROWS * 96 * 2 + 64;
    unsigned short* h1b = (unsigned short*)p;  p += (size_t)NROWS * 96 * 2 + 64;
    unsigned short* h2b = (unsigned short*)p;  p += (size_t)NROWS * 96 * 2 + 64;

    // ---- adjacency build + converts (one grid) ----
    hipMemsetAsync(deg, 0, 50176 * sizeof(int), stream);
    build_cvt<<<EB + CB + WB + 1, 256, 0, stream>>>(
        src, dst, deg, colu, x, h0b, h1b, h2b,
        Wl0, Wr0, Wl1, Wr1, Wl2, Wr2, WT0, WT1, WT2);

    // ---- layers (fused gather + MFMA), 16 nodes / 256 threads per block ----
    const int LB = NNODES / 16;   // 3125 exact
    fused_layer<6, true><<<LB, 256, 0, stream>>>(h0b, deg, colu, WT0, b0, h1b, nullptr);
    fused_layer<6, true><<<LB, 256, 0, stream>>>(h1b, deg, colu, WT1, b1, h2b, nullptr);
    fused_layer<3, false><<<LB, 256, 0, stream>>>(h2b, deg, colu, WT2, b2, nullptr, out);
}